// Round 4
// baseline (475.637 us; speedup 1.0000x reference)
//
#include <hip/hip_runtime.h>

typedef unsigned short u16;
typedef unsigned int u32;
typedef unsigned char u8;
typedef short bf16x8 __attribute__((ext_vector_type(8)));
typedef float f32x4 __attribute__((ext_vector_type(4)));
typedef float f32x16 __attribute__((ext_vector_type(16)));
typedef int i32x4 __attribute__((ext_vector_type(4)));
typedef int i32x8 __attribute__((ext_vector_type(8)));

#define AS1 __attribute__((address_space(1)))
#define AS3 __attribute__((address_space(3)))

#define B_ 2
#define T_ 2048
#define DIM_ 1024
#define HID_ 4096
#define H_ 16
#define KVH_ 4
#define HD_ 64
#define WIN_ 512

// MX scale bytes: activations stored x8 (descale 2^-3 = 124), weights x64 (2^-6 = 121)
#define SCALE_A 0x7C7C7C7C
#define SCALE_B 0x79797979

__device__ __forceinline__ u16 f2bf(float f) {
    union { float f; u32 u; } v; v.f = f;
    u32 r = v.u + 0x7FFFu + ((v.u >> 16) & 1u);
    return (u16)(r >> 16);
}
__device__ __forceinline__ float bf2f(u32 u) {
    union { u32 u; float f; } v; v.u = u << 16;
    return v.f;
}
__device__ __forceinline__ float4 ld4bf(const u16* p) {
    uint2 u = *(const uint2*)p;
    float4 r;
    r.x = bf2f(u.x & 0xFFFFu); r.y = bf2f(u.x >> 16);
    r.z = bf2f(u.y & 0xFFFFu); r.w = bf2f(u.y >> 16);
    return r;
}
__device__ __forceinline__ void load_lds16(const void* g, void* l) {
    __builtin_amdgcn_global_load_lds((AS1 void*)(g), (AS3 void*)(l), 16, 0, 0);
}

// ---------------- mega convert: bf16 for wqkv/wo, fp8(x64) for w13 (interleaved-32) & w2 ----------------
__global__ __launch_bounds__(256) void mega_cvt(const float* __restrict__ wq,
                                                const float* __restrict__ wk,
                                                const float* __restrict__ wv,
                                                const float* __restrict__ wo,
                                                const float* __restrict__ w1,
                                                const float* __restrict__ w3,
                                                const float* __restrict__ w2,
                                                u16* __restrict__ wqkv,
                                                u16* __restrict__ wo_b,
                                                u8* __restrict__ w13_8,
                                                u8* __restrict__ w2_8) {
    int i = blockIdx.x * 256 + threadIdx.x;  // global float4 index, < 3801088 exactly
    if (i < 655360) {
        const float* s; uint2* dbase; size_t didx;
        if (i < 262144)      { s = wq + (size_t)i * 4; dbase = (uint2*)wqkv; didx = i; }
        else if (i < 327680) { int f = i - 262144; s = wk + (size_t)f * 4; dbase = (uint2*)wqkv; didx = 262144 + f; }
        else if (i < 393216) { int f = i - 327680; s = wv + (size_t)f * 4; dbase = (uint2*)wqkv; didx = 327680 + f; }
        else                 { int f = i - 393216; s = wo + (size_t)f * 4; dbase = (uint2*)wo_b; didx = f; }
        float4 v = *(const float4*)s;
        u32 lo = (u32)f2bf(v.x) | ((u32)f2bf(v.y) << 16);
        u32 hi = (u32)f2bf(v.z) | ((u32)f2bf(v.w) << 16);
        dbase[didx] = make_uint2(lo, hi);
    } else {
        // fp8 e4m3, values x64. w1/w3 interleaved in 32-col tiles:
        //   w1 row c -> packed (c>>5)*64 + (c&31);  w3 row c -> packed (c>>5)*64 + 32 + (c&31)
        const float* s; u32* dbase; size_t didx;
        if (i < 1703936)      { int f = i - 655360;  int c = f >> 8; int n = (c >> 5) * 64 + (c & 31);
                                s = w1 + (size_t)f * 4; dbase = (u32*)w13_8; didx = (size_t)n * 256 + (f & 255); }
        else if (i < 2752512) { int f = i - 1703936; int c = f >> 8; int n = (c >> 5) * 64 + 32 + (c & 31);
                                s = w3 + (size_t)f * 4; dbase = (u32*)w13_8; didx = (size_t)n * 256 + (f & 255); }
        else                  { int f = i - 2752512; s = w2 + (size_t)f * 4; dbase = (u32*)w2_8; didx = f; }
        float4 v = *(const float4*)s;
        int p = __builtin_amdgcn_cvt_pk_fp8_f32(v.x * 64.f, v.y * 64.f, 0, false);
        p = __builtin_amdgcn_cvt_pk_fp8_f32(v.z * 64.f, v.w * 64.f, p, true);
        dbase[didx] = (u32)p;
    }
}

// ---------------- RMSNorm (fp32 in, bf16 out), dim=1024 ----------------
__global__ __launch_bounds__(256) void rmsnorm_kernel(const float* __restrict__ x,
                                                      const float* __restrict__ w,
                                                      u16* __restrict__ out, float eps) {
    int row = blockIdx.x, tid = threadIdx.x;
    const float4 v = ((const float4*)(x + (size_t)row * DIM_))[tid];
    float ss = v.x * v.x + v.y * v.y + v.z * v.z + v.w * v.w;
#pragma unroll
    for (int m = 1; m < 64; m <<= 1) ss += __shfl_xor(ss, m);
    __shared__ float part[4];
    if ((tid & 63) == 0) part[tid >> 6] = ss;
    __syncthreads();
    float tot = part[0] + part[1] + part[2] + part[3];
    float r = rsqrtf(tot * (1.0f / DIM_) + eps);
    const float4 wv = ((const float4*)w)[tid];
    u32 lo = (u32)f2bf(v.x * r * wv.x) | ((u32)f2bf(v.y * r * wv.y) << 16);
    u32 hi = (u32)f2bf(v.z * r * wv.z) | ((u32)f2bf(v.w * r * wv.w) << 16);
    ((uint2*)(out + (size_t)row * DIM_))[tid] = make_uint2(lo, hi);
}

// ---------------- fuse_attn: h = x + (p0+p1)*ascale; xn8 = fp8(rmsnorm(h)*fnw * 8) ----------------
__global__ __launch_bounds__(256) void fuse_attn_kernel(const float* __restrict__ x,
                                                        const u16* __restrict__ p,
                                                        const float* __restrict__ ascale,
                                                        const float* __restrict__ fnw,
                                                        float* __restrict__ h,
                                                        u8* __restrict__ xn8) {
    int row = blockIdx.x, tid = threadIdx.x;
    const float4 xv = ((const float4*)(x + (size_t)row * DIM_))[tid];
    float4 a0 = ld4bf(p + (size_t)row * DIM_ + tid * 4);
    float4 a1 = ld4bf(p + 4194304 + (size_t)row * DIM_ + tid * 4);
    const float4 sc = ((const float4*)ascale)[tid];
    float4 hv;
    hv.x = xv.x + (a0.x + a1.x) * sc.x;
    hv.y = xv.y + (a0.y + a1.y) * sc.y;
    hv.z = xv.z + (a0.z + a1.z) * sc.z;
    hv.w = xv.w + (a0.w + a1.w) * sc.w;
    ((float4*)(h + (size_t)row * DIM_))[tid] = hv;
    float ss = hv.x * hv.x + hv.y * hv.y + hv.z * hv.z + hv.w * hv.w;
#pragma unroll
    for (int m = 1; m < 64; m <<= 1) ss += __shfl_xor(ss, m);
    __shared__ float part[4];
    if ((tid & 63) == 0) part[tid >> 6] = ss;
    __syncthreads();
    float tot = part[0] + part[1] + part[2] + part[3];
    float r = rsqrtf(tot * (1.0f / DIM_) + 1e-5f) * 8.0f;  // x8 for fp8 encoding
    const float4 wv = ((const float4*)fnw)[tid];
    int pk = __builtin_amdgcn_cvt_pk_fp8_f32(hv.x * r * wv.x, hv.y * r * wv.y, 0, false);
    pk = __builtin_amdgcn_cvt_pk_fp8_f32(hv.z * r * wv.z, hv.w * r * wv.w, pk, true);
    ((u32*)xn8)[(size_t)row * 256 + tid] = (u32)pk;
}

// ---------------- fuse_ffn: out = h + (p0+p1+p2+p3)*fscale (bf16 partials) ----------------
__global__ __launch_bounds__(256) void fuse_ffn_kernel(const float* __restrict__ h,
                                                       const u16* __restrict__ p,
                                                       const float* __restrict__ fscale,
                                                       float* __restrict__ out) {
    int row = blockIdx.x, tid = threadIdx.x;
    const float4 hv = ((const float4*)(h + (size_t)row * DIM_))[tid];
    size_t off = (size_t)row * DIM_ + tid * 4;
    float4 a0 = ld4bf(p + off);
    float4 a1 = ld4bf(p + 4194304 + off);
    float4 a2 = ld4bf(p + 8388608 + off);
    float4 a3 = ld4bf(p + 12582912 + off);
    const float4 sc = ((const float4*)fscale)[tid];
    float4 o;
    o.x = hv.x + (a0.x + a1.x + a2.x + a3.x) * sc.x;
    o.y = hv.y + (a0.y + a1.y + a2.y + a3.y) * sc.y;
    o.z = hv.z + (a0.z + a1.z + a2.z + a3.z) * sc.z;
    o.w = hv.w + (a0.w + a1.w + a2.w + a3.w) * sc.w;
    ((float4*)(out + (size_t)row * DIM_))[tid] = o;
}

// ---------------- QKV post: sum 2 bf16 partials + per-head RMSNorm(1e-6) + bf16 pack ----------------
__global__ __launch_bounds__(256) void qkv_post_kernel(const u16* __restrict__ qkv,
                                                       const float* __restrict__ qw,
                                                       const float* __restrict__ kw,
                                                       u16* __restrict__ Qb,
                                                       u16* __restrict__ Kb,
                                                       u16* __restrict__ Vb) {
    int bt = blockIdx.x;
    int b = bt >> 11, t = bt & (T_ - 1);
    int wave = threadIdx.x >> 6, lane = threadIdx.x & 63;
    const u16* row0 = qkv + (size_t)bt * 1536;
    const u16* row1 = row0 + 6291456;
    float qwl = qw[lane], kwl = kw[lane];
#pragma unroll
    for (int i = 0; i < 4; i++) {
        int h = wave * 4 + i;
        float v = bf2f(row0[h * 64 + lane]) + bf2f(row1[h * 64 + lane]);
        float ss = v * v;
#pragma unroll
        for (int m = 1; m < 64; m <<= 1) ss += __shfl_xor(ss, m);
        float r = rsqrtf(ss * (1.0f / 64.0f) + 1e-6f);
        Qb[(((size_t)(b * H_ + h)) * T_ + t) * HD_ + lane] = f2bf(v * r * qwl);
    }
    {
        float v = bf2f(row0[1024 + wave * 64 + lane]) + bf2f(row1[1024 + wave * 64 + lane]);
        float ss = v * v;
#pragma unroll
        for (int m = 1; m < 64; m <<= 1) ss += __shfl_xor(ss, m);
        float r = rsqrtf(ss * (1.0f / 64.0f) + 1e-6f);
        Kb[(((size_t)(b * KVH_ + wave)) * T_ + t) * HD_ + lane] = f2bf(v * r * kwl);
        float vv = bf2f(row0[1280 + wave * 64 + lane]) + bf2f(row1[1280 + wave * 64 + lane]);
        Vb[(((size_t)(b * KVH_ + wave)) * T_ + t) * HD_ + lane] = f2bf(vv);
    }
}

// ---------------- V transpose: Vb [bk][T][64] -> Vt [bk][64][T], 64x64 tiles ----------------
__global__ __launch_bounds__(256) void vtrans_kernel(const u16* __restrict__ Vb,
                                                     u16* __restrict__ Vt) {
    const int bk = blockIdx.x >> 5;          // b*KVH+kvh, 0..7
    const int t0 = (blockIdx.x & 31) * 64;
    const int tid = threadIdx.x;
    __shared__ __align__(16) u16 tile[64][64];
    const u16* src = Vb + ((size_t)bk * T_ + t0) * HD_;
#pragma unroll
    for (int i = 0; i < 2; i++) {
        int g = tid + i * 256;               // granule 0..511 over [64 rows][8 granules]
        int r = g >> 3, c8 = g & 7;
        *(bf16x8*)&tile[r][c8 * 8] = *(const bf16x8*)(src + (size_t)r * HD_ + c8 * 8);
    }
    __syncthreads();
    const int d = tid >> 2, ts = (tid & 3) * 16;
    u16 buf[16];
#pragma unroll
    for (int j = 0; j < 16; j++) buf[j] = tile[ts + j][d];
    u16* dst = Vt + (size_t)bk * HD_ * T_ + (size_t)d * T_ + t0 + ts;
    *(bf16x8*)(dst) = *(const bf16x8*)&buf[0];
    *(bf16x8*)(dst + 8) = *(const bf16x8*)&buf[8];
}

// ---------------- Flash attention, sliding window 512, GQA 16/4 ----------------
// 8 waves per block: wave = (half, qw). Each qw (16 q-rows) has its KV window split
// between half=0 (older tiles) and half=1 (newer tiles, incl. diagonal); the two
// partial (o, m, l) states merge through LDS with one barrier. Doubles waves/SIMD
// (latency-bound kernel, occupancy was 28%) and halves the per-wave serial chain.
// K read direct from global (L2-resident), V from pre-transposed Vt.
// NaN guard: mrun sentinel -1e30f (finite) also makes empty-half merge exact:
// alpha = exp(-1e30 - m) = 0.
__global__ __launch_bounds__(512, 8) void flash_kernel(const u16* __restrict__ Qb,
                                                       const u16* __restrict__ Kb,
                                                       const u16* __restrict__ Vt,
                                                       u16* __restrict__ Ob) {
    const int b = blockIdx.z, h = blockIdx.y, qt = blockIdx.x;
    const int q0 = qt * 64;
    const int tid = threadIdx.x, wave = tid >> 6, lane = tid & 63;
    const int qw = wave & 3, half = wave >> 2;
    const int m = lane & 15, quad = lane >> 4;
    const int kvh = h >> 2;

    __shared__ __align__(16) u16 Ps[8][16 * 40];
    __shared__ __align__(16) float CombO[4][64][16];
    __shared__ float CombML[4][64][8];

    const u16* Qp = Qb + ((size_t)(b * H_ + h) * T_) * HD_;
    const u16* Kp = Kb + ((size_t)(b * KVH_ + kvh) * T_) * HD_;
    const u16* Vp = Vt + ((size_t)(b * KVH_ + kvh) * HD_) * T_;

    const int qlo = q0 + qw * 16;            // this pair's rows [qlo, qlo+15]
    const int qrow = qlo + m;
    bf16x8 qa0 = *(const bf16x8*)(Qp + (size_t)qrow * 64 + quad * 8);
    bf16x8 qa1 = *(const bf16x8*)(Qp + (size_t)qrow * 64 + 32 + quad * 8);

    f32x4 o0 = {0.f, 0.f, 0.f, 0.f}, o1 = {0.f, 0.f, 0.f, 0.f};
    f32x4 o2 = {0.f, 0.f, 0.f, 0.f}, o3 = {0.f, 0.f, 0.f, 0.f};
    float mrun[4] = {-1e30f, -1e30f, -1e30f, -1e30f};
    float lrun[4] = {0.f, 0.f, 0.f, 0.f};

    const int klo = (qlo - (WIN_ - 1) > 0) ? (qlo - (WIN_ - 1)) : 0;
    const int kt0 = klo >> 5, kt1 = (qlo + 15) >> 5;
    const int nLo = (kt1 - kt0 + 1) >> 1;
    const int myKt0 = half ? (kt0 + nLo) : kt0;
    const int myKt1 = half ? kt1 : (kt0 + nLo - 1);

    // prologue: first K tile into registers (in-bounds even if range empty)
    const u16* kp0 = Kp + (size_t)(myKt0 * 32 + m) * 64 + quad * 8;
    bf16x8 k00 = *(const bf16x8*)(kp0);
    bf16x8 k01 = *(const bf16x8*)(kp0 + 32);
    bf16x8 k10 = *(const bf16x8*)(kp0 + 16 * 64);
    bf16x8 k11 = *(const bf16x8*)(kp0 + 16 * 64 + 32);

    for (int kt = myKt0; kt <= myKt1; ++kt) {
        const int kbase = kt << 5;
        f32x4 s0 = {0.f, 0.f, 0.f, 0.f}, s1 = {0.f, 0.f, 0.f, 0.f};
        s0 = __builtin_amdgcn_mfma_f32_16x16x32_bf16(qa0, k00, s0, 0, 0, 0);
        s0 = __builtin_amdgcn_mfma_f32_16x16x32_bf16(qa1, k01, s0, 0, 0, 0);
        s1 = __builtin_amdgcn_mfma_f32_16x16x32_bf16(qa0, k10, s1, 0, 0, 0);
        s1 = __builtin_amdgcn_mfma_f32_16x16x32_bf16(qa1, k11, s1, 0, 0, 0);
        // V fragments for this tile (issued early; consumed after softmax)
        const u16* vp = Vp + (size_t)m * T_ + kbase + quad * 8;
        bf16x8 vb0 = *(const bf16x8*)(vp);
        bf16x8 vb1 = *(const bf16x8*)(vp + 16 * T_);
        bf16x8 vb2 = *(const bf16x8*)(vp + 32 * T_);
        bf16x8 vb3 = *(const bf16x8*)(vp + 48 * T_);
        // register prefetch of next K tile (latency hidden under softmax)
        if (kt < myKt1) {
            const u16* kp = Kp + (size_t)(kbase + 32 + m) * 64 + quad * 8;
            k00 = *(const bf16x8*)(kp);
            k01 = *(const bf16x8*)(kp + 32);
            k10 = *(const bf16x8*)(kp + 16 * 64);
            k11 = *(const bf16x8*)(kp + 16 * 64 + 32);
        }
        const bool full = (kbase + 31 <= qlo) && (kbase >= qlo - 496);
#pragma unroll
        for (int r = 0; r < 4; r++) {
            float v0, v1;
            if (full) {
                v0 = s0[r] * 0.125f;
                v1 = s1[r] * 0.125f;
            } else {
                int qg = qlo + quad * 4 + r;
                int kg0 = kbase + m, kg1 = kbase + 16 + m;
                v0 = (kg0 <= qg && qg - kg0 < WIN_) ? s0[r] * 0.125f : -INFINITY;
                v1 = (kg1 <= qg && qg - kg1 < WIN_) ? s1[r] * 0.125f : -INFINITY;
            }
            float rmax = fmaxf(v0, v1);
            rmax = fmaxf(rmax, __shfl_xor(rmax, 1));
            rmax = fmaxf(rmax, __shfl_xor(rmax, 2));
            rmax = fmaxf(rmax, __shfl_xor(rmax, 4));
            rmax = fmaxf(rmax, __shfl_xor(rmax, 8));
            float mnew = fmaxf(mrun[r], rmax);      // finite: >= -1e30 sentinel
            float alpha = __expf(mrun[r] - mnew);   // both finite -> no NaN
            float p0 = __expf(v0 - mnew);           // exp(-inf - finite) = 0 for masked
            float p1 = __expf(v1 - mnew);
            float psum = p0 + p1;
            psum += __shfl_xor(psum, 1);
            psum += __shfl_xor(psum, 2);
            psum += __shfl_xor(psum, 4);
            psum += __shfl_xor(psum, 8);
            lrun[r] = lrun[r] * alpha + psum;
            mrun[r] = mnew;
            o0[r] *= alpha; o1[r] *= alpha; o2[r] *= alpha; o3[r] *= alpha;
            Ps[wave][(quad * 4 + r) * 40 + m] = f2bf(p0);
            Ps[wave][(quad * 4 + r) * 40 + 16 + m] = f2bf(p1);
        }
        bf16x8 pa = *(const bf16x8*)&Ps[wave][m * 40 + quad * 8];
        o0 = __builtin_amdgcn_mfma_f32_16x16x32_bf16(pa, vb0, o0, 0, 0, 0);
        o1 = __builtin_amdgcn_mfma_f32_16x16x32_bf16(pa, vb1, o1, 0, 0, 0);
        o2 = __builtin_amdgcn_mfma_f32_16x16x32_bf16(pa, vb2, o2, 0, 0, 0);
        o3 = __builtin_amdgcn_mfma_f32_16x16x32_bf16(pa, vb3, o3, 0, 0, 0);
    }

    // ---- cross-half merge ----
    if (half) {
        float* co = &CombO[qw][lane][0];
        *(f32x4*)(co + 0) = o0;
        *(f32x4*)(co + 4) = o1;
        *(f32x4*)(co + 8) = o2;
        *(f32x4*)(co + 12) = o3;
        float* cm = &CombML[qw][lane][0];
        cm[0] = mrun[0]; cm[1] = mrun[1]; cm[2] = mrun[2]; cm[3] = mrun[3];
        cm[4] = lrun[0]; cm[5] = lrun[1]; cm[6] = lrun[2]; cm[7] = lrun[3];
    }
    __syncthreads();
    if (!half) {
        const float* co = &CombO[qw][lane][0];
        const float* cm = &CombML[qw][lane][0];
        f32x4 u0 = *(const f32x4*)(co + 0);
        f32x4 u1 = *(const f32x4*)(co + 4);
        f32x4 u2 = *(const f32x4*)(co + 8);
        f32x4 u3 = *(const f32x4*)(co + 12);
#pragma unroll
        for (int r = 0; r < 4; r++) {
            float m1 = cm[r], l1 = cm[4 + r];
            float mf = fmaxf(mrun[r], m1);
            float a0 = __expf(mrun[r] - mf);        // 0 if this half empty
            float a1 = __expf(m1 - mf);             // 0 if other half empty
            float inv = 1.0f / (lrun[r] * a0 + l1 * a1);
            float b0 = a0 * inv, b1 = a1 * inv;
            int qg = qlo + quad * 4 + r;
            size_t base = ((size_t)(b * T_ + qg)) * (H_ * HD_) + h * HD_;
            Ob[base + 0 + m]  = f2bf(o0[r] * b0 + u0[r] * b1);
            Ob[base + 16 + m] = f2bf(o1[r] * b0 + u1[r] * b1);
            Ob[base + 32 + m] = f2bf(o2[r] * b0 + u2[r] * b1);
            Ob[base + 48 + m] = f2bf(o3[r] * b0 + u3[r] * b1);
        }
    }
}

// ---------------- bf16 GEMM, double-buffered single-barrier K-loop ----------------
// Prefetch tile k+1 is issued AFTER the barrier (which drains tile k's loads via its
// implicit vmcnt(0)) so it overlaps the ds_read+MFMA of tile k.
__global__ __launch_bounds__(256) void gemm_bt(const u16* __restrict__ A,
                                               const u16* __restrict__ Bt,
                                               u16* __restrict__ Cb,
                                               int M, int N, int K, int KS) {
    __shared__ __align__(16) u16 As[2][4096];
    __shared__ __align__(16) u16 Bs[2][4096];
    const int tid = threadIdx.x, wave = tid >> 6, lane = tid & 63;
    const int m = lane & 15, quad = lane >> 4;
    const int m0 = blockIdx.y * 128, n0 = blockIdx.x * 128;
    const int wm = (wave >> 1) * 64, wn = (wave & 1) * 64;
    const int kb = blockIdx.z * KS;
    const int nIter = KS >> 5;
    const int slot = wave * 2;
    const int flat0 = slot * 512 + lane * 8;
    const int row0_ = flat0 >> 5, col0 = flat0 & 31;
    const int flat1 = (slot + 1) * 512 + lane * 8;
    const int row1_ = flat1 >> 5, col1 = flat1 & 31;

    f32x4 acc[4][4] = {};

    // prologue: stage tile 0 into buffer 0
    load_lds16(A + (size_t)(m0 + row0_) * K + kb + col0, &As[0][slot * 512]);
    load_lds16(Bt + (size_t)(n0 + row0_) * K + kb + col0, &Bs[0][slot * 512]);
    load_lds16(A + (size_t)(m0 + row1_) * K + kb + col1, &As[0][(slot + 1) * 512]);
    load_lds16(Bt + (size_t)(n0 + row1_) * K + kb + col1, &Bs[0][(slot + 1) * 512]);

    for (int it = 0; it < nIter; ++it) {
        __syncthreads();  // drains vmcnt -> tile `it` staged; all waves done computing it-1
        const int cur = it & 1;
        if (it + 1 < nIter) {
            const int nb = 1 - cur;
            const int k0 = kb + (it + 1) * 32;
            load_lds16(A + (size_t)(m0 + row0_) * K + k0 + col0, &As[nb][slot * 512]);
            load_lds16(Bt + (size_t)(n0 + row0_) * K + k0 + col0, &Bs[nb][slot * 512]);
            load_lds16(A + (size_t)(m0 + row1_) * K + k0 + col1, &As[nb][(slot + 1) * 512]);
            load_lds16(Bt + (size_t)(n0 + row1_) * K + k0 + col1, &Bs[nb][(slot + 1) * 512]);
        }
        bf16x8 af[4], bfr[4];
#pragma unroll
        for (int i = 0; i < 4; i++) af[i] = *(const bf16x8*)&As[cur][(wm + i * 16 + m) * 32 + quad * 8];
#pragma unroll
        for (int j = 0; j < 4; j++) bfr[j] = *(const bf16x8*)&Bs[cur][(wn + j * 16 + m) * 32 + quad * 8];
#pragma unroll
        for (int i = 0; i < 4; i++)
#pragma unroll
            for (int j = 0; j < 4; j++)
                acc[i][j] = __builtin_amdgcn_mfma_f32_16x16x32_bf16(af[i], bfr[j], acc[i][j], 0, 0, 0);
    }

    u16* Cz = Cb + (size_t)blockIdx.z * M * N;
#pragma unroll
    for (int i = 0; i < 4; i++) {
        int rowb = m0 + wm + i * 16 + quad * 4;
#pragma unroll
        for (int j = 0; j < 4; j++) {
            int col = n0 + wn + j * 16 + m;
#pragma unroll
            for (int r = 0; r < 4; r++)
                Cz[(size_t)(rowb + r) * N + col] = f2bf(acc[i][j][r]);
        }
    }
}

// ---------------- fp8 MX GEMM (32x32x64 f8f6f4), 256x256 tile, 4-phase counted-vmcnt ----------------
// A [M][K] fp8 (x8), Bt [N][K] fp8 (x64). Tile 256x256, BK=128, 8 waves (2M x 4N),
// per-wave output 128x64 = acc[4][2] of 32x32. LDS 128 KiB: 2 dbuf x (A 32KB + B 32KB).
// Tile layout: granule (chunk c, row r) -> offset (c*256 + r)*16, c in [0,8) (= k-bytes c*16..+16).
// Staging quantum = one k-slice (4 chunks) of one matrix = 16KB = 2 global_load_lds/thread.
// Per K-tile: 4 phases, each {stage 1 quantum of tile t+1; [vmcnt(6)+barrier on phases 0,2]; 4 MFMA}.
// vmcnt is COUNTED (3 quanta = 6 loads in flight), never 0 in the main loop (T3+T4).
// MODE 0: bf16 partials at z*M*N. MODE 1: fused SwiGLU (32-col interleave) -> fp8(x8).
#define MFMA8(a, b, c) __builtin_amdgcn_mfma_scale_f32_32x32x64_f8f6f4(a, b, c, 0, 0, 0, SCALE_A, 0, SCALE_B)
#define WAITBAR(N) asm volatile("s_waitcnt vmcnt(" #N ")\n\ts_barrier" ::: "memory")
#define PHASE_MFMA(I0, I1)                           \
    __builtin_amdgcn_s_setprio(1);                   \
    acc[I0][0] = MFMA8(a0, bf0, acc[I0][0]);         \
    acc[I0][1] = MFMA8(a0, bf1, acc[I0][1]);         \
    acc[I1][0] = MFMA8(a1, bf0, acc[I1][0]);         \
    acc[I1][1] = MFMA8(a1, bf1, acc[I1][1]);         \
    __builtin_amdgcn_s_setprio(0);

template <int MODE>
__global__ __launch_bounds__(512) void gemm_fp8(const u8* __restrict__ A,
                                                const u8* __restrict__ Bt,
                                                u16* __restrict__ Cb,
                                                u8* __restrict__ C8,
                                                int M, int N, int K, int KS) {
    __shared__ __align__(16) u8 As[2][32768];
    __shared__ __align__(16) u8 Bs[2][32768];
    const int tid = threadIdx.x, wave = tid >> 6, lane = tid & 63;
    const int l31 = lane & 31, lh = lane >> 5;
    const int m0 = blockIdx.y * 256, n0 = blockIdx.x * 256;
    const int wm = (wave >> 2) * 128, wn = (wave & 3) * 64;
    const int kb = blockIdx.z * KS;
    const int KT = KS >> 7;

    // staging addressing: thread covers source row srow = (wave&3)*64 + lane,
    // chunks ch = ks*4 + (wave>>2) + 2q. LDS dest is wave-uniform (HW adds lane*16).
    const int srow = ((wave & 3) << 6) + lane;
    const u8* Asrc = A + (size_t)m0 * K + (size_t)srow * K;
    const u8* Bsrc = Bt + (size_t)n0 * K + (size_t)srow * K;
    const int wv2 = wave >> 2;
    const int ldsW = (wave & 3) << 10;

    auto STAGE = [&](const u8* src, int kk, int ks, u8* lds) {
#pragma unroll
        for (int q = 0; q < 2; q++) {
            const int ch = ks * 4 + wv2 + 2 * q;
            load_lds16(src + kk + ch * 16, lds + (ch << 12) + ldsW);
        }
    };
    auto FRAG = [&](const u8* t, int ks, int row) -> i32x8 {
        const int c0 = ks * 4 + (lh << 1);
        union { i32x4 h[2]; i32x8 v; } u;
        u.h[0] = *(const i32x4*)(t + ((c0 << 8) + row) * 16);
        u.h[1] = *(const i32x4*)(t + (((c0 + 1) << 8) + row) * 16);
        return u.v;
    };

    f32x16 acc[4][2] = {};

    // prologue: stage tile 0 into buffer 0 (issue order = A-k0, B-k0, A-k1, B-k1)
    STAGE(Asrc, kb, 0, As[0]);
    STAGE(Bsrc, kb, 0, Bs[0]);
    STAGE(Asrc, kb, 1, As[0]);
    STAGE(Bsrc, kb, 1, Bs[0]);

    for (int kt = 0; kt < KT - 1; ++kt) {
        const int cur = kt & 1, nb = cur ^ 1;
        const u8* Ac = As[cur];
        const u8* Bc = Bs[cur];
        const int kn = kb + (kt + 1) * 128;
        i32x8 bf0, bf1, a0, a1;
        // ---- phase 0: ks=0, i in {0,1}; needs A-k0(t),B-k0(t); 3 quanta stay in flight
        STAGE(Asrc, kn, 0, As[nb]);
        WAITBAR(6);
        bf0 = FRAG(Bc, 0, wn + l31);
        bf1 = FRAG(Bc, 0, wn + 32 + l31);
        a0 = FRAG(Ac, 0, wm + l31);
        a1 = FRAG(Ac, 0, wm + 32 + l31);
        PHASE_MFMA(0, 1)
        // ---- phase 1: ks=0, i in {2,3} (reuse bf0/bf1)
        STAGE(Bsrc, kn, 0, Bs[nb]);
        a0 = FRAG(Ac, 0, wm + 64 + l31);
        a1 = FRAG(Ac, 0, wm + 96 + l31);
        PHASE_MFMA(2, 3)
        // ---- phase 2: ks=1, i in {0,1}; needs A-k1(t),B-k1(t)
        STAGE(Asrc, kn, 1, As[nb]);
        WAITBAR(6);
        bf0 = FRAG(Bc, 1, wn + l31);
        bf1 = FRAG(Bc, 1, wn + 32 + l31);
        a0 = FRAG(Ac, 1, wm + l31);
        a1 = FRAG(Ac, 1, wm + 32 + l31);
        PHASE_MFMA(0, 1)
        // ---- phase 3: ks=1, i in {2,3}
        STAGE(Bsrc, kn, 1, Bs[nb]);
        a0 = FRAG(Ac, 1, wm + 64 + l31);
        a1 = FRAG(Ac, 1, wm + 96 + l31);
        PHASE_MFMA(2, 3)
    }
    // epilogue tile KT-1 (no prefetch): drain 4 -> 0
    {
        const int cur = (KT - 1) & 1;
        const u8* Ac = As[cur];
        const u8* Bc = Bs[cur];
        i32x8 bf0, bf1, a0, a1;
        WAITBAR(4);
        bf0 = FRAG(Bc, 0, wn + l31);
        bf1 = FRAG(Bc, 0, wn + 32 + l31);
        a0 = FRAG(Ac, 0, wm + l31);
        a1 = FRAG(Ac, 0, wm + 32 + l31);
        PHASE_MFMA(0, 1)
        a0 = FRAG(Ac, 0, wm + 64 + l31);
        a1 = FRAG(Ac, 0, wm + 96 + l31);
        PHASE_MFMA(2, 3)
        WAITBAR(0);
        bf0 = FRAG(Bc, 1, wn + l31);
        bf1 = FRAG(Bc, 1, wn + 32 + l31);
        a0 = FRAG(Ac, 1, wm + l31);
        a1 = FRAG(Ac, 1, wm + 32 + l31);
        PHASE_MFMA(0, 1)
        a0 = FRAG(Ac, 1, wm + 64 + l31);
        a1 = FRAG(Ac, 1, wm + 96 + l31);
        PHASE_MFMA(2, 3)
    }

    if (MODE == 0) {
        u16* Cz = Cb + (size_t)blockIdx.z * M * N;
#pragma unroll
        for (int i = 0; i < 4; i++)
#pragma unroll
            for (int j = 0; j < 2; j++) {
                int col = n0 + wn + j * 32 + l31;
#pragma unroll
                for (int reg = 0; reg < 16; reg++) {
                    int row = m0 + wm + i * 32 + (reg & 3) + 8 * (reg >> 2) + 4 * lh;
                    Cz[(size_t)row * N + col] = f2bf(acc[i][j][reg]);
                }
            }
    } else {
        // SwiGLU: acc[i][0] = g1-tile, acc[i][1] = g3-tile for same 32 real cols
        int c = (n0 >> 1) + (wn >> 1) + l31;
#pragma unroll
        for (int i = 0; i < 4; i++)
#pragma unroll
            for (int reg = 0; reg < 16; reg++) {
                int row = m0 + wm + i * 32 + (reg & 3) + 8 * (reg >> 2) + 4 * lh;
                float g1 = acc[i][0][reg], g3 = acc[i][1][reg];
                float res = (g1 / (1.f + __expf(-g1))) * g3 * 8.0f;  // x8 for fp8 encoding
                int p = __builtin_amdgcn_cvt_pk_fp8_f32(res, res, 0, false);
                C8[(size_t)row * (N >> 1) + c] = (u8)(p & 0xFF);
            }
    }
}

extern "C" void kernel_launch(void* const* d_in, const int* in_sizes, int n_in,
                              void* d_out, int out_size, void* d_ws, size_t ws_size,
                              hipStream_t stream) {
    const float* x = (const float*)d_in[0];
    const float* wq = (const float*)d_in[1];
    const float* wk = (const float*)d_in[2];
    const float* wv = (const float*)d_in[3];
    const float* wo = (const float*)d_in[4];
    const float* w1 = (const float*)d_in[5];
    const float* w2 = (const float*)d_in[6];
    const float* w3 = (const float*)d_in[7];
    const float* qnw = (const float*)d_in[8];
    const float* knw = (const float*)d_in[9];
    const float* anw = (const float*)d_in[10];
    const float* fnw = (const float*)d_in[11];
    const float* ascale = (const float*)d_in[12];
    const float* fscale = (const float*)d_in[13];
    float* out = (float*)d_out;

    // ---- workspace layout (~109 MiB) ----
    char* ws = (char*)d_ws;
    u16* wqkv_bf = (u16*)(ws + 0);          // [1536][1024] bf16
    u16* wo_bf = (u16*)(ws + 3145728);      // [1024][1024] bf16
    u8* w13_8 = (u8*)(ws + 5242880);        // [8192][1024] fp8 (x64, 32-col interleave)
    u8* w2_8 = (u8*)(ws + 13631488);        // [1024][4096] fp8 (x64)
    u16* xn_bf = (u16*)(ws + 17825792);     // [4096][1024] bf16 (attn-norm out)
    u8* xn8 = (u8*)(ws + 26214400);         // [4096][1024] fp8 (x8, ffn-norm out)
    float* h_f = (float*)(ws + 30408704);   // [4096][1024] fp32
    char* P = ws + 47185920;                // overlay pool (67.1 MB)
    u16* qkv_part = (u16*)(P + 0);          // 2x[4096][1536] bf16 partials
    u16* Qb = (u16*)(P + 25165824);
    u16* Kb = (u16*)(P + 33554432);
    u16* Vb = (u16*)(P + 35651584);
    u16* att_bf = (u16*)(P + 37748736);     // [4096][1024] bf16
    u16* Vt = (u16*)(P + 46137344);         // [8][64][2048] bf16 (V transposed; dead after flash)
    u16* wo_part = (u16*)(P + 0);           // 2x[4096][1024] bf16 (reuses qkv_part)
    u8* gsw8 = (u8*)(P + 16777216);         // [4096][4096] fp8 (after wo_part)
    u16* w2_part = (u16*)(P + 33554432);    // 4x[4096][1024] bf16 (after att/flash done)

    mega_cvt<<<14848, 256, 0, stream>>>(wq, wk, wv, wo, w1, w3, w2,
                                        wqkv_bf, wo_bf, w13_8, w2_8);
    rmsnorm_kernel<<<4096, 256, 0, stream>>>(x, anw, xn_bf, 1e-5f);
    // QKV projection, split-K=2 -> bf16 partials
    gemm_bt<<<dim3(12, 32, 2), 256, 0, stream>>>(xn_bf, wqkv_bf, qkv_part,
                                                 4096, 1536, 1024, 512);
    qkv_post_kernel<<<4096, 256, 0, stream>>>(qkv_part, qnw, knw, Qb, Kb, Vb);
    vtrans_kernel<<<256, 256, 0, stream>>>(Vb, Vt);
    flash_kernel<<<dim3(32, 16, 2), 512, 0, stream>>>(Qb, Kb, Vt, att_bf);
    // out-proj, split-K=2 -> bf16 partials
    gemm_bt<<<dim3(8, 32, 2), 256, 0, stream>>>(att_bf, wo_bf, wo_part,
                                                4096, 1024, 1024, 512);
    fuse_attn_kernel<<<4096, 256, 0, stream>>>(x, wo_part, ascale, fnw, h_f, xn8);
    // w1|w3 fp8-MX GEMM with fused SwiGLU -> gsw8 (256x256 tiles, 512 blocks = 2 full CU rounds)
    gemm_fp8<1><<<dim3(32, 16, 1), 512, 0, stream>>>(xn8, w13_8, nullptr, gsw8,
                                                     4096, 8192, 1024, 1024);
    // w2 fp8-MX GEMM, split-K=4 -> bf16 partials (256 blocks = exactly 1 CU round)
    gemm_fp8<0><<<dim3(4, 16, 4), 512, 0, stream>>>(gsw8, w2_8, w2_part, nullptr,
                                                    4096, 1024, 4096, 1024);
    fuse_ffn_kernel<<<4096, 256, 0, stream>>>(h_f, w2_part, fscale, out);
}

// Round 5
// 354.979 us; speedup vs baseline: 1.3399x; 1.3399x over previous
//
#include <hip/hip_runtime.h>

typedef unsigned short u16;
typedef unsigned int u32;
typedef unsigned char u8;
typedef short bf16x8 __attribute__((ext_vector_type(8)));
typedef float f32x4 __attribute__((ext_vector_type(4)));
typedef float f32x16 __attribute__((ext_vector_type(16)));
typedef int i32x4 __attribute__((ext_vector_type(4)));
typedef int i32x8 __attribute__((ext_vector_type(8)));

#define AS1 __attribute__((address_space(1)))
#define AS3 __attribute__((address_space(3)))

#define B_ 2
#define T_ 2048
#define DIM_ 1024
#define HID_ 4096
#define H_ 16
#define KVH_ 4
#define HD_ 64
#define WIN_ 512

// MX scale bytes: activations stored x8 (descale 2^-3 = 124), weights x64 (2^-6 = 121)
#define SCALE_A 0x7C7C7C7C
#define SCALE_B 0x79797979

__device__ __forceinline__ u16 f2bf(float f) {
    union { float f; u32 u; } v; v.f = f;
    u32 r = v.u + 0x7FFFu + ((v.u >> 16) & 1u);
    return (u16)(r >> 16);
}
__device__ __forceinline__ float bf2f(u32 u) {
    union { u32 u; float f; } v; v.u = u << 16;
    return v.f;
}
__device__ __forceinline__ float4 ld4bf(const u16* p) {
    uint2 u = *(const uint2*)p;
    float4 r;
    r.x = bf2f(u.x & 0xFFFFu); r.y = bf2f(u.x >> 16);
    r.z = bf2f(u.y & 0xFFFFu); r.w = bf2f(u.y >> 16);
    return r;
}
__device__ __forceinline__ void load_lds16(const void* g, void* l) {
    __builtin_amdgcn_global_load_lds((AS1 void*)(g), (AS3 void*)(l), 16, 0, 0);
}

// ---------------- mega convert: bf16 for wqkv/wo, fp8(x64) for w13 (interleaved-32) & w2 ----------------
__global__ __launch_bounds__(256) void mega_cvt(const float* __restrict__ wq,
                                                const float* __restrict__ wk,
                                                const float* __restrict__ wv,
                                                const float* __restrict__ wo,
                                                const float* __restrict__ w1,
                                                const float* __restrict__ w3,
                                                const float* __restrict__ w2,
                                                u16* __restrict__ wqkv,
                                                u16* __restrict__ wo_b,
                                                u8* __restrict__ w13_8,
                                                u8* __restrict__ w2_8) {
    int i = blockIdx.x * 256 + threadIdx.x;  // global float4 index, < 3801088 exactly
    if (i < 655360) {
        const float* s; uint2* dbase; size_t didx;
        if (i < 262144)      { s = wq + (size_t)i * 4; dbase = (uint2*)wqkv; didx = i; }
        else if (i < 327680) { int f = i - 262144; s = wk + (size_t)f * 4; dbase = (uint2*)wqkv; didx = 262144 + f; }
        else if (i < 393216) { int f = i - 327680; s = wv + (size_t)f * 4; dbase = (uint2*)wqkv; didx = 327680 + f; }
        else                 { int f = i - 393216; s = wo + (size_t)f * 4; dbase = (uint2*)wo_b; didx = f; }
        float4 v = *(const float4*)s;
        u32 lo = (u32)f2bf(v.x) | ((u32)f2bf(v.y) << 16);
        u32 hi = (u32)f2bf(v.z) | ((u32)f2bf(v.w) << 16);
        dbase[didx] = make_uint2(lo, hi);
    } else {
        // fp8 e4m3, values x64. w1/w3 interleaved in 32-col tiles:
        //   w1 row c -> packed (c>>5)*64 + (c&31);  w3 row c -> packed (c>>5)*64 + 32 + (c&31)
        const float* s; u32* dbase; size_t didx;
        if (i < 1703936)      { int f = i - 655360;  int c = f >> 8; int n = (c >> 5) * 64 + (c & 31);
                                s = w1 + (size_t)f * 4; dbase = (u32*)w13_8; didx = (size_t)n * 256 + (f & 255); }
        else if (i < 2752512) { int f = i - 1703936; int c = f >> 8; int n = (c >> 5) * 64 + 32 + (c & 31);
                                s = w3 + (size_t)f * 4; dbase = (u32*)w13_8; didx = (size_t)n * 256 + (f & 255); }
        else                  { int f = i - 2752512; s = w2 + (size_t)f * 4; dbase = (u32*)w2_8; didx = f; }
        float4 v = *(const float4*)s;
        int p = __builtin_amdgcn_cvt_pk_fp8_f32(v.x * 64.f, v.y * 64.f, 0, false);
        p = __builtin_amdgcn_cvt_pk_fp8_f32(v.z * 64.f, v.w * 64.f, p, true);
        dbase[didx] = (u32)p;
    }
}

// ---------------- RMSNorm (fp32 in, bf16 out), dim=1024 ----------------
__global__ __launch_bounds__(256) void rmsnorm_kernel(const float* __restrict__ x,
                                                      const float* __restrict__ w,
                                                      u16* __restrict__ out, float eps) {
    int row = blockIdx.x, tid = threadIdx.x;
    const float4 v = ((const float4*)(x + (size_t)row * DIM_))[tid];
    float ss = v.x * v.x + v.y * v.y + v.z * v.z + v.w * v.w;
#pragma unroll
    for (int m = 1; m < 64; m <<= 1) ss += __shfl_xor(ss, m);
    __shared__ float part[4];
    if ((tid & 63) == 0) part[tid >> 6] = ss;
    __syncthreads();
    float tot = part[0] + part[1] + part[2] + part[3];
    float r = rsqrtf(tot * (1.0f / DIM_) + eps);
    const float4 wv = ((const float4*)w)[tid];
    u32 lo = (u32)f2bf(v.x * r * wv.x) | ((u32)f2bf(v.y * r * wv.y) << 16);
    u32 hi = (u32)f2bf(v.z * r * wv.z) | ((u32)f2bf(v.w * r * wv.w) << 16);
    ((uint2*)(out + (size_t)row * DIM_))[tid] = make_uint2(lo, hi);
}

// ---------------- fuse_attn: h = x + (p0+p1)*ascale; xn8 = fp8(rmsnorm(h)*fnw * 8) ----------------
__global__ __launch_bounds__(256) void fuse_attn_kernel(const float* __restrict__ x,
                                                        const u16* __restrict__ p,
                                                        const float* __restrict__ ascale,
                                                        const float* __restrict__ fnw,
                                                        float* __restrict__ h,
                                                        u8* __restrict__ xn8) {
    int row = blockIdx.x, tid = threadIdx.x;
    const float4 xv = ((const float4*)(x + (size_t)row * DIM_))[tid];
    float4 a0 = ld4bf(p + (size_t)row * DIM_ + tid * 4);
    float4 a1 = ld4bf(p + 4194304 + (size_t)row * DIM_ + tid * 4);
    const float4 sc = ((const float4*)ascale)[tid];
    float4 hv;
    hv.x = xv.x + (a0.x + a1.x) * sc.x;
    hv.y = xv.y + (a0.y + a1.y) * sc.y;
    hv.z = xv.z + (a0.z + a1.z) * sc.z;
    hv.w = xv.w + (a0.w + a1.w) * sc.w;
    ((float4*)(h + (size_t)row * DIM_))[tid] = hv;
    float ss = hv.x * hv.x + hv.y * hv.y + hv.z * hv.z + hv.w * hv.w;
#pragma unroll
    for (int m = 1; m < 64; m <<= 1) ss += __shfl_xor(ss, m);
    __shared__ float part[4];
    if ((tid & 63) == 0) part[tid >> 6] = ss;
    __syncthreads();
    float tot = part[0] + part[1] + part[2] + part[3];
    float r = rsqrtf(tot * (1.0f / DIM_) + 1e-5f) * 8.0f;  // x8 for fp8 encoding
    const float4 wv = ((const float4*)fnw)[tid];
    int pk = __builtin_amdgcn_cvt_pk_fp8_f32(hv.x * r * wv.x, hv.y * r * wv.y, 0, false);
    pk = __builtin_amdgcn_cvt_pk_fp8_f32(hv.z * r * wv.z, hv.w * r * wv.w, pk, true);
    ((u32*)xn8)[(size_t)row * 256 + tid] = (u32)pk;
}

// ---------------- fuse_ffn: out = h + (p0+p1+p2+p3)*fscale (bf16 partials) ----------------
__global__ __launch_bounds__(256) void fuse_ffn_kernel(const float* __restrict__ h,
                                                       const u16* __restrict__ p,
                                                       const float* __restrict__ fscale,
                                                       float* __restrict__ out) {
    int row = blockIdx.x, tid = threadIdx.x;
    const float4 hv = ((const float4*)(h + (size_t)row * DIM_))[tid];
    size_t off = (size_t)row * DIM_ + tid * 4;
    float4 a0 = ld4bf(p + off);
    float4 a1 = ld4bf(p + 4194304 + off);
    float4 a2 = ld4bf(p + 8388608 + off);
    float4 a3 = ld4bf(p + 12582912 + off);
    const float4 sc = ((const float4*)fscale)[tid];
    float4 o;
    o.x = hv.x + (a0.x + a1.x + a2.x + a3.x) * sc.x;
    o.y = hv.y + (a0.y + a1.y + a2.y + a3.y) * sc.y;
    o.z = hv.z + (a0.z + a1.z + a2.z + a3.z) * sc.z;
    o.w = hv.w + (a0.w + a1.w + a2.w + a3.w) * sc.w;
    ((float4*)(out + (size_t)row * DIM_))[tid] = o;
}

// ---------------- QKV post: sum 2 bf16 partials + per-head RMSNorm(1e-6) + bf16 pack ----------------
__global__ __launch_bounds__(256) void qkv_post_kernel(const u16* __restrict__ qkv,
                                                       const float* __restrict__ qw,
                                                       const float* __restrict__ kw,
                                                       u16* __restrict__ Qb,
                                                       u16* __restrict__ Kb,
                                                       u16* __restrict__ Vb) {
    int bt = blockIdx.x;
    int b = bt >> 11, t = bt & (T_ - 1);
    int wave = threadIdx.x >> 6, lane = threadIdx.x & 63;
    const u16* row0 = qkv + (size_t)bt * 1536;
    const u16* row1 = row0 + 6291456;
    float qwl = qw[lane], kwl = kw[lane];
#pragma unroll
    for (int i = 0; i < 4; i++) {
        int h = wave * 4 + i;
        float v = bf2f(row0[h * 64 + lane]) + bf2f(row1[h * 64 + lane]);
        float ss = v * v;
#pragma unroll
        for (int m = 1; m < 64; m <<= 1) ss += __shfl_xor(ss, m);
        float r = rsqrtf(ss * (1.0f / 64.0f) + 1e-6f);
        Qb[(((size_t)(b * H_ + h)) * T_ + t) * HD_ + lane] = f2bf(v * r * qwl);
    }
    {
        float v = bf2f(row0[1024 + wave * 64 + lane]) + bf2f(row1[1024 + wave * 64 + lane]);
        float ss = v * v;
#pragma unroll
        for (int m = 1; m < 64; m <<= 1) ss += __shfl_xor(ss, m);
        float r = rsqrtf(ss * (1.0f / 64.0f) + 1e-6f);
        Kb[(((size_t)(b * KVH_ + wave)) * T_ + t) * HD_ + lane] = f2bf(v * r * kwl);
        float vv = bf2f(row0[1280 + wave * 64 + lane]) + bf2f(row1[1280 + wave * 64 + lane]);
        Vb[(((size_t)(b * KVH_ + wave)) * T_ + t) * HD_ + lane] = f2bf(vv);
    }
}

// ---------------- V transpose: Vb [bk][T][64] -> Vt [bk][64][T], 64x64 tiles ----------------
__global__ __launch_bounds__(256) void vtrans_kernel(const u16* __restrict__ Vb,
                                                     u16* __restrict__ Vt) {
    const int bk = blockIdx.x >> 5;          // b*KVH+kvh, 0..7
    const int t0 = (blockIdx.x & 31) * 64;
    const int tid = threadIdx.x;
    __shared__ __align__(16) u16 tile[64][64];
    const u16* src = Vb + ((size_t)bk * T_ + t0) * HD_;
#pragma unroll
    for (int i = 0; i < 2; i++) {
        int g = tid + i * 256;               // granule 0..511 over [64 rows][8 granules]
        int r = g >> 3, c8 = g & 7;
        *(bf16x8*)&tile[r][c8 * 8] = *(const bf16x8*)(src + (size_t)r * HD_ + c8 * 8);
    }
    __syncthreads();
    const int d = tid >> 2, ts = (tid & 3) * 16;
    u16 buf[16];
#pragma unroll
    for (int j = 0; j < 16; j++) buf[j] = tile[ts + j][d];
    u16* dst = Vt + (size_t)bk * HD_ * T_ + (size_t)d * T_ + t0 + ts;
    *(bf16x8*)(dst) = *(const bf16x8*)&buf[0];
    *(bf16x8*)(dst + 8) = *(const bf16x8*)&buf[8];
}

// ---------------- Flash attention, sliding window 512, GQA 16/4 ----------------
// 8 waves per block: wave = (half, qw). Each qw (16 q-rows) has its KV window split
// between half=0 (older tiles) and half=1 (newer tiles, incl. diagonal); the two
// partial (o, m, l) states merge through LDS with one barrier.
// LAUNCH BOUNDS: (512, 4) -> VGPR cap 128. Round 4's (512, 8) capped VGPR at 64,
// allocator squeezed to 32 and spilled the whole working set to scratch:
// FETCH 287 MB / WRITE 402 MB per dispatch (vs 19/8 expected), 2.5x slower.
// The kernel naturally wants ~64-90 VGPR; LDS 34.8 KB -> 4 blocks/CU still gives
// up to 32 waves/CU when VGPR <= 64, 24+/CU at 85.
// K read direct from global (L2-resident), V from pre-transposed Vt.
// NaN guard: mrun sentinel -1e30f (finite) also makes empty-half merge exact.
__global__ __launch_bounds__(512, 4) void flash_kernel(const u16* __restrict__ Qb,
                                                       const u16* __restrict__ Kb,
                                                       const u16* __restrict__ Vt,
                                                       u16* __restrict__ Ob) {
    const int b = blockIdx.z, h = blockIdx.y, qt = blockIdx.x;
    const int q0 = qt * 64;
    const int tid = threadIdx.x, wave = tid >> 6, lane = tid & 63;
    const int qw = wave & 3, half = wave >> 2;
    const int m = lane & 15, quad = lane >> 4;
    const int kvh = h >> 2;

    __shared__ __align__(16) u16 Ps[8][16 * 40];
    __shared__ __align__(16) float CombO[4][64][16];
    __shared__ float CombML[4][64][8];

    const u16* Qp = Qb + ((size_t)(b * H_ + h) * T_) * HD_;
    const u16* Kp = Kb + ((size_t)(b * KVH_ + kvh) * T_) * HD_;
    const u16* Vp = Vt + ((size_t)(b * KVH_ + kvh) * HD_) * T_;

    const int qlo = q0 + qw * 16;            // this pair's rows [qlo, qlo+15]
    const int qrow = qlo + m;
    bf16x8 qa0 = *(const bf16x8*)(Qp + (size_t)qrow * 64 + quad * 8);
    bf16x8 qa1 = *(const bf16x8*)(Qp + (size_t)qrow * 64 + 32 + quad * 8);

    f32x4 o0 = {0.f, 0.f, 0.f, 0.f}, o1 = {0.f, 0.f, 0.f, 0.f};
    f32x4 o2 = {0.f, 0.f, 0.f, 0.f}, o3 = {0.f, 0.f, 0.f, 0.f};
    float mrun[4] = {-1e30f, -1e30f, -1e30f, -1e30f};
    float lrun[4] = {0.f, 0.f, 0.f, 0.f};

    const int klo = (qlo - (WIN_ - 1) > 0) ? (qlo - (WIN_ - 1)) : 0;
    const int kt0 = klo >> 5, kt1 = (qlo + 15) >> 5;
    const int nLo = (kt1 - kt0 + 1) >> 1;
    const int myKt0 = half ? (kt0 + nLo) : kt0;
    const int myKt1 = half ? kt1 : (kt0 + nLo - 1);

    // prologue: first K tile into registers (in-bounds even if range empty)
    const u16* kp0 = Kp + (size_t)(myKt0 * 32 + m) * 64 + quad * 8;
    bf16x8 k00 = *(const bf16x8*)(kp0);
    bf16x8 k01 = *(const bf16x8*)(kp0 + 32);
    bf16x8 k10 = *(const bf16x8*)(kp0 + 16 * 64);
    bf16x8 k11 = *(const bf16x8*)(kp0 + 16 * 64 + 32);

    for (int kt = myKt0; kt <= myKt1; ++kt) {
        const int kbase = kt << 5;
        f32x4 s0 = {0.f, 0.f, 0.f, 0.f}, s1 = {0.f, 0.f, 0.f, 0.f};
        s0 = __builtin_amdgcn_mfma_f32_16x16x32_bf16(qa0, k00, s0, 0, 0, 0);
        s0 = __builtin_amdgcn_mfma_f32_16x16x32_bf16(qa1, k01, s0, 0, 0, 0);
        s1 = __builtin_amdgcn_mfma_f32_16x16x32_bf16(qa0, k10, s1, 0, 0, 0);
        s1 = __builtin_amdgcn_mfma_f32_16x16x32_bf16(qa1, k11, s1, 0, 0, 0);
        // V fragments for this tile (issued early; consumed after softmax)
        const u16* vp = Vp + (size_t)m * T_ + kbase + quad * 8;
        bf16x8 vb0 = *(const bf16x8*)(vp);
        bf16x8 vb1 = *(const bf16x8*)(vp + 16 * T_);
        bf16x8 vb2 = *(const bf16x8*)(vp + 32 * T_);
        bf16x8 vb3 = *(const bf16x8*)(vp + 48 * T_);
        // register prefetch of next K tile (latency hidden under softmax)
        if (kt < myKt1) {
            const u16* kp = Kp + (size_t)(kbase + 32 + m) * 64 + quad * 8;
            k00 = *(const bf16x8*)(kp);
            k01 = *(const bf16x8*)(kp + 32);
            k10 = *(const bf16x8*)(kp + 16 * 64);
            k11 = *(const bf16x8*)(kp + 16 * 64 + 32);
        }
        const bool full = (kbase + 31 <= qlo) && (kbase >= qlo - 496);
#pragma unroll
        for (int r = 0; r < 4; r++) {
            float v0, v1;
            if (full) {
                v0 = s0[r] * 0.125f;
                v1 = s1[r] * 0.125f;
            } else {
                int qg = qlo + quad * 4 + r;
                int kg0 = kbase + m, kg1 = kbase + 16 + m;
                v0 = (kg0 <= qg && qg - kg0 < WIN_) ? s0[r] * 0.125f : -INFINITY;
                v1 = (kg1 <= qg && qg - kg1 < WIN_) ? s1[r] * 0.125f : -INFINITY;
            }
            float rmax = fmaxf(v0, v1);
            rmax = fmaxf(rmax, __shfl_xor(rmax, 1));
            rmax = fmaxf(rmax, __shfl_xor(rmax, 2));
            rmax = fmaxf(rmax, __shfl_xor(rmax, 4));
            rmax = fmaxf(rmax, __shfl_xor(rmax, 8));
            float mnew = fmaxf(mrun[r], rmax);      // finite: >= -1e30 sentinel
            float alpha = __expf(mrun[r] - mnew);   // both finite -> no NaN
            float p0 = __expf(v0 - mnew);           // exp(-inf - finite) = 0 for masked
            float p1 = __expf(v1 - mnew);
            float psum = p0 + p1;
            psum += __shfl_xor(psum, 1);
            psum += __shfl_xor(psum, 2);
            psum += __shfl_xor(psum, 4);
            psum += __shfl_xor(psum, 8);
            lrun[r] = lrun[r] * alpha + psum;
            mrun[r] = mnew;
            o0[r] *= alpha; o1[r] *= alpha; o2[r] *= alpha; o3[r] *= alpha;
            Ps[wave][(quad * 4 + r) * 40 + m] = f2bf(p0);
            Ps[wave][(quad * 4 + r) * 40 + 16 + m] = f2bf(p1);
        }
        bf16x8 pa = *(const bf16x8*)&Ps[wave][m * 40 + quad * 8];
        o0 = __builtin_amdgcn_mfma_f32_16x16x32_bf16(pa, vb0, o0, 0, 0, 0);
        o1 = __builtin_amdgcn_mfma_f32_16x16x32_bf16(pa, vb1, o1, 0, 0, 0);
        o2 = __builtin_amdgcn_mfma_f32_16x16x32_bf16(pa, vb2, o2, 0, 0, 0);
        o3 = __builtin_amdgcn_mfma_f32_16x16x32_bf16(pa, vb3, o3, 0, 0, 0);
    }

    // ---- cross-half merge ----
    if (half) {
        float* co = &CombO[qw][lane][0];
        *(f32x4*)(co + 0) = o0;
        *(f32x4*)(co + 4) = o1;
        *(f32x4*)(co + 8) = o2;
        *(f32x4*)(co + 12) = o3;
        float* cm = &CombML[qw][lane][0];
        cm[0] = mrun[0]; cm[1] = mrun[1]; cm[2] = mrun[2]; cm[3] = mrun[3];
        cm[4] = lrun[0]; cm[5] = lrun[1]; cm[6] = lrun[2]; cm[7] = lrun[3];
    }
    __syncthreads();
    if (!half) {
        const float* co = &CombO[qw][lane][0];
        const float* cm = &CombML[qw][lane][0];
        f32x4 u0 = *(const f32x4*)(co + 0);
        f32x4 u1 = *(const f32x4*)(co + 4);
        f32x4 u2 = *(const f32x4*)(co + 8);
        f32x4 u3 = *(const f32x4*)(co + 12);
#pragma unroll
        for (int r = 0; r < 4; r++) {
            float m1 = cm[r], l1 = cm[4 + r];
            float mf = fmaxf(mrun[r], m1);
            float a0 = __expf(mrun[r] - mf);        // 0 if this half empty
            float a1 = __expf(m1 - mf);             // 0 if other half empty
            float inv = 1.0f / (lrun[r] * a0 + l1 * a1);
            float b0 = a0 * inv, b1 = a1 * inv;
            int qg = qlo + quad * 4 + r;
            size_t base = ((size_t)(b * T_ + qg)) * (H_ * HD_) + h * HD_;
            Ob[base + 0 + m]  = f2bf(o0[r] * b0 + u0[r] * b1);
            Ob[base + 16 + m] = f2bf(o1[r] * b0 + u1[r] * b1);
            Ob[base + 32 + m] = f2bf(o2[r] * b0 + u2[r] * b1);
            Ob[base + 48 + m] = f2bf(o3[r] * b0 + u3[r] * b1);
        }
    }
}

// ---------------- bf16 GEMM, double-buffered single-barrier K-loop ----------------
// Prefetch tile k+1 is issued AFTER the barrier (which drains tile k's loads via its
// implicit vmcnt(0)) so it overlaps the ds_read+MFMA of tile k.
__global__ __launch_bounds__(256) void gemm_bt(const u16* __restrict__ A,
                                               const u16* __restrict__ Bt,
                                               u16* __restrict__ Cb,
                                               int M, int N, int K, int KS) {
    __shared__ __align__(16) u16 As[2][4096];
    __shared__ __align__(16) u16 Bs[2][4096];
    const int tid = threadIdx.x, wave = tid >> 6, lane = tid & 63;
    const int m = lane & 15, quad = lane >> 4;
    const int m0 = blockIdx.y * 128, n0 = blockIdx.x * 128;
    const int wm = (wave >> 1) * 64, wn = (wave & 1) * 64;
    const int kb = blockIdx.z * KS;
    const int nIter = KS >> 5;
    const int slot = wave * 2;
    const int flat0 = slot * 512 + lane * 8;
    const int row0_ = flat0 >> 5, col0 = flat0 & 31;
    const int flat1 = (slot + 1) * 512 + lane * 8;
    const int row1_ = flat1 >> 5, col1 = flat1 & 31;

    f32x4 acc[4][4] = {};

    // prologue: stage tile 0 into buffer 0
    load_lds16(A + (size_t)(m0 + row0_) * K + kb + col0, &As[0][slot * 512]);
    load_lds16(Bt + (size_t)(n0 + row0_) * K + kb + col0, &Bs[0][slot * 512]);
    load_lds16(A + (size_t)(m0 + row1_) * K + kb + col1, &As[0][(slot + 1) * 512]);
    load_lds16(Bt + (size_t)(n0 + row1_) * K + kb + col1, &Bs[0][(slot + 1) * 512]);

    for (int it = 0; it < nIter; ++it) {
        __syncthreads();  // drains vmcnt -> tile `it` staged; all waves done computing it-1
        const int cur = it & 1;
        if (it + 1 < nIter) {
            const int nb = 1 - cur;
            const int k0 = kb + (it + 1) * 32;
            load_lds16(A + (size_t)(m0 + row0_) * K + k0 + col0, &As[nb][slot * 512]);
            load_lds16(Bt + (size_t)(n0 + row0_) * K + k0 + col0, &Bs[nb][slot * 512]);
            load_lds16(A + (size_t)(m0 + row1_) * K + k0 + col1, &As[nb][(slot + 1) * 512]);
            load_lds16(Bt + (size_t)(n0 + row1_) * K + k0 + col1, &Bs[nb][(slot + 1) * 512]);
        }
        bf16x8 af[4], bfr[4];
#pragma unroll
        for (int i = 0; i < 4; i++) af[i] = *(const bf16x8*)&As[cur][(wm + i * 16 + m) * 32 + quad * 8];
#pragma unroll
        for (int j = 0; j < 4; j++) bfr[j] = *(const bf16x8*)&Bs[cur][(wn + j * 16 + m) * 32 + quad * 8];
#pragma unroll
        for (int i = 0; i < 4; i++)
#pragma unroll
            for (int j = 0; j < 4; j++)
                acc[i][j] = __builtin_amdgcn_mfma_f32_16x16x32_bf16(af[i], bfr[j], acc[i][j], 0, 0, 0);
    }

    u16* Cz = Cb + (size_t)blockIdx.z * M * N;
#pragma unroll
    for (int i = 0; i < 4; i++) {
        int rowb = m0 + wm + i * 16 + quad * 4;
#pragma unroll
        for (int j = 0; j < 4; j++) {
            int col = n0 + wn + j * 16 + m;
#pragma unroll
            for (int r = 0; r < 4; r++)
                Cz[(size_t)(rowb + r) * N + col] = f2bf(acc[i][j][r]);
        }
    }
}

// ---------------- fp8 MX GEMM (32x32x64 f8f6f4), 256x256 tile, 4-phase counted-vmcnt ----------------
// A [M][K] fp8 (x8), Bt [N][K] fp8 (x64). Tile 256x256, BK=128, 8 waves (2M x 4N),
// per-wave output 128x64 = acc[4][2] of 32x32. LDS 128 KiB: 2 dbuf x (A 32KB + B 32KB).
// Tile layout: granule (chunk c, row r) -> offset (c*256 + r)*16, c in [0,8) (= k-bytes c*16..+16).
// Staging quantum = one k-slice (4 chunks) of one matrix = 16KB = 2 global_load_lds/thread.
// Per K-tile: 4 phases, each {stage 1 quantum of tile t+1; [vmcnt(6)+barrier on phases 0,2]; 4 MFMA}.
// vmcnt is COUNTED (3 quanta = 6 loads in flight), never 0 in the main loop (T3+T4).
// MODE 0: bf16 partials at z*M*N. MODE 1: fused SwiGLU (32-col interleave) -> fp8(x8).
#define MFMA8(a, b, c) __builtin_amdgcn_mfma_scale_f32_32x32x64_f8f6f4(a, b, c, 0, 0, 0, SCALE_A, 0, SCALE_B)
#define WAITBAR(N) asm volatile("s_waitcnt vmcnt(" #N ")\n\ts_barrier" ::: "memory")
#define PHASE_MFMA(I0, I1)                           \
    __builtin_amdgcn_s_setprio(1);                   \
    acc[I0][0] = MFMA8(a0, bf0, acc[I0][0]);         \
    acc[I0][1] = MFMA8(a0, bf1, acc[I0][1]);         \
    acc[I1][0] = MFMA8(a1, bf0, acc[I1][0]);         \
    acc[I1][1] = MFMA8(a1, bf1, acc[I1][1]);         \
    __builtin_amdgcn_s_setprio(0);

template <int MODE>
__global__ __launch_bounds__(512) void gemm_fp8(const u8* __restrict__ A,
                                                const u8* __restrict__ Bt,
                                                u16* __restrict__ Cb,
                                                u8* __restrict__ C8,
                                                int M, int N, int K, int KS) {
    __shared__ __align__(16) u8 As[2][32768];
    __shared__ __align__(16) u8 Bs[2][32768];
    const int tid = threadIdx.x, wave = tid >> 6, lane = tid & 63;
    const int l31 = lane & 31, lh = lane >> 5;
    const int m0 = blockIdx.y * 256, n0 = blockIdx.x * 256;
    const int wm = (wave >> 2) * 128, wn = (wave & 3) * 64;
    const int kb = blockIdx.z * KS;
    const int KT = KS >> 7;

    // staging addressing: thread covers source row srow = (wave&3)*64 + lane,
    // chunks ch = ks*4 + (wave>>2) + 2q. LDS dest is wave-uniform (HW adds lane*16).
    const int srow = ((wave & 3) << 6) + lane;
    const u8* Asrc = A + (size_t)m0 * K + (size_t)srow * K;
    const u8* Bsrc = Bt + (size_t)n0 * K + (size_t)srow * K;
    const int wv2 = wave >> 2;
    const int ldsW = (wave & 3) << 10;

    auto STAGE = [&](const u8* src, int kk, int ks, u8* lds) {
#pragma unroll
        for (int q = 0; q < 2; q++) {
            const int ch = ks * 4 + wv2 + 2 * q;
            load_lds16(src + kk + ch * 16, lds + (ch << 12) + ldsW);
        }
    };
    auto FRAG = [&](const u8* t, int ks, int row) -> i32x8 {
        const int c0 = ks * 4 + (lh << 1);
        union { i32x4 h[2]; i32x8 v; } u;
        u.h[0] = *(const i32x4*)(t + ((c0 << 8) + row) * 16);
        u.h[1] = *(const i32x4*)(t + (((c0 + 1) << 8) + row) * 16);
        return u.v;
    };

    f32x16 acc[4][2] = {};

    // prologue: stage tile 0 into buffer 0 (issue order = A-k0, B-k0, A-k1, B-k1)
    STAGE(Asrc, kb, 0, As[0]);
    STAGE(Bsrc, kb, 0, Bs[0]);
    STAGE(Asrc, kb, 1, As[0]);
    STAGE(Bsrc, kb, 1, Bs[0]);

    for (int kt = 0; kt < KT - 1; ++kt) {
        const int cur = kt & 1, nb = cur ^ 1;
        const u8* Ac = As[cur];
        const u8* Bc = Bs[cur];
        const int kn = kb + (kt + 1) * 128;
        i32x8 bf0, bf1, a0, a1;
        // ---- phase 0: ks=0, i in {0,1}; needs A-k0(t),B-k0(t); 3 quanta stay in flight
        STAGE(Asrc, kn, 0, As[nb]);
        WAITBAR(6);
        bf0 = FRAG(Bc, 0, wn + l31);
        bf1 = FRAG(Bc, 0, wn + 32 + l31);
        a0 = FRAG(Ac, 0, wm + l31);
        a1 = FRAG(Ac, 0, wm + 32 + l31);
        PHASE_MFMA(0, 1)
        // ---- phase 1: ks=0, i in {2,3} (reuse bf0/bf1)
        STAGE(Bsrc, kn, 0, Bs[nb]);
        a0 = FRAG(Ac, 0, wm + 64 + l31);
        a1 = FRAG(Ac, 0, wm + 96 + l31);
        PHASE_MFMA(2, 3)
        // ---- phase 2: ks=1, i in {0,1}; needs A-k1(t),B-k1(t)
        STAGE(Asrc, kn, 1, As[nb]);
        WAITBAR(6);
        bf0 = FRAG(Bc, 1, wn + l31);
        bf1 = FRAG(Bc, 1, wn + 32 + l31);
        a0 = FRAG(Ac, 1, wm + l31);
        a1 = FRAG(Ac, 1, wm + 32 + l31);
        PHASE_MFMA(0, 1)
        // ---- phase 3: ks=1, i in {2,3}
        STAGE(Bsrc, kn, 1, Bs[nb]);
        a0 = FRAG(Ac, 1, wm + 64 + l31);
        a1 = FRAG(Ac, 1, wm + 96 + l31);
        PHASE_MFMA(2, 3)
    }
    // epilogue tile KT-1 (no prefetch): drain 4 -> 0
    {
        const int cur = (KT - 1) & 1;
        const u8* Ac = As[cur];
        const u8* Bc = Bs[cur];
        i32x8 bf0, bf1, a0, a1;
        WAITBAR(4);
        bf0 = FRAG(Bc, 0, wn + l31);
        bf1 = FRAG(Bc, 0, wn + 32 + l31);
        a0 = FRAG(Ac, 0, wm + l31);
        a1 = FRAG(Ac, 0, wm + 32 + l31);
        PHASE_MFMA(0, 1)
        a0 = FRAG(Ac, 0, wm + 64 + l31);
        a1 = FRAG(Ac, 0, wm + 96 + l31);
        PHASE_MFMA(2, 3)
        WAITBAR(0);
        bf0 = FRAG(Bc, 1, wn + l31);
        bf1 = FRAG(Bc, 1, wn + 32 + l31);
        a0 = FRAG(Ac, 1, wm + l31);
        a1 = FRAG(Ac, 1, wm + 32 + l31);
        PHASE_MFMA(0, 1)
        a0 = FRAG(Ac, 1, wm + 64 + l31);
        a1 = FRAG(Ac, 1, wm + 96 + l31);
        PHASE_MFMA(2, 3)
    }

    if (MODE == 0) {
        u16* Cz = Cb + (size_t)blockIdx.z * M * N;
#pragma unroll
        for (int i = 0; i < 4; i++)
#pragma unroll
            for (int j = 0; j < 2; j++) {
                int col = n0 + wn + j * 32 + l31;
#pragma unroll
                for (int reg = 0; reg < 16; reg++) {
                    int row = m0 + wm + i * 32 + (reg & 3) + 8 * (reg >> 2) + 4 * lh;
                    Cz[(size_t)row * N + col] = f2bf(acc[i][j][reg]);
                }
            }
    } else {
        // SwiGLU: acc[i][0] = g1-tile, acc[i][1] = g3-tile for same 32 real cols
        int c = (n0 >> 1) + (wn >> 1) + l31;
#pragma unroll
        for (int i = 0; i < 4; i++)
#pragma unroll
            for (int reg = 0; reg < 16; reg++) {
                int row = m0 + wm + i * 32 + (reg & 3) + 8 * (reg >> 2) + 4 * lh;
                float g1 = acc[i][0][reg], g3 = acc[i][1][reg];
                float res = (g1 / (1.f + __expf(-g1))) * g3 * 8.0f;  // x8 for fp8 encoding
                int p = __builtin_amdgcn_cvt_pk_fp8_f32(res, res, 0, false);
                C8[(size_t)row * (N >> 1) + c] = (u8)(p & 0xFF);
            }
    }
}

extern "C" void kernel_launch(void* const* d_in, const int* in_sizes, int n_in,
                              void* d_out, int out_size, void* d_ws, size_t ws_size,
                              hipStream_t stream) {
    const float* x = (const float*)d_in[0];
    const float* wq = (const float*)d_in[1];
    const float* wk = (const float*)d_in[2];
    const float* wv = (const float*)d_in[3];
    const float* wo = (const float*)d_in[4];
    const float* w1 = (const float*)d_in[5];
    const float* w2 = (const float*)d_in[6];
    const float* w3 = (const float*)d_in[7];
    const float* qnw = (const float*)d_in[8];
    const float* knw = (const float*)d_in[9];
    const float* anw = (const float*)d_in[10];
    const float* fnw = (const float*)d_in[11];
    const float* ascale = (const float*)d_in[12];
    const float* fscale = (const float*)d_in[13];
    float* out = (float*)d_out;

    // ---- workspace layout (~109 MiB) ----
    char* ws = (char*)d_ws;
    u16* wqkv_bf = (u16*)(ws + 0);          // [1536][1024] bf16
    u16* wo_bf = (u16*)(ws + 3145728);      // [1024][1024] bf16
    u8* w13_8 = (u8*)(ws + 5242880);        // [8192][1024] fp8 (x64, 32-col interleave)
    u8* w2_8 = (u8*)(ws + 13631488);        // [1024][4096] fp8 (x64)
    u16* xn_bf = (u16*)(ws + 17825792);     // [4096][1024] bf16 (attn-norm out)
    u8* xn8 = (u8*)(ws + 26214400);         // [4096][1024] fp8 (x8, ffn-norm out)
    float* h_f = (float*)(ws + 30408704);   // [4096][1024] fp32
    char* P = ws + 47185920;                // overlay pool (67.1 MB)
    u16* qkv_part = (u16*)(P + 0);          // 2x[4096][1536] bf16 partials
    u16* Qb = (u16*)(P + 25165824);
    u16* Kb = (u16*)(P + 33554432);
    u16* Vb = (u16*)(P + 35651584);
    u16* att_bf = (u16*)(P + 37748736);     // [4096][1024] bf16
    u16* Vt = (u16*)(P + 46137344);         // [8][64][2048] bf16 (V transposed; dead after flash)
    u16* wo_part = (u16*)(P + 0);           // 2x[4096][1024] bf16 (reuses qkv_part)
    u8* gsw8 = (u8*)(P + 16777216);         // [4096][4096] fp8 (after wo_part)
    u16* w2_part = (u16*)(P + 33554432);    // 4x[4096][1024] bf16 (after att/flash done)

    mega_cvt<<<14848, 256, 0, stream>>>(wq, wk, wv, wo, w1, w3, w2,
                                        wqkv_bf, wo_bf, w13_8, w2_8);
    rmsnorm_kernel<<<4096, 256, 0, stream>>>(x, anw, xn_bf, 1e-5f);
    // QKV projection, split-K=2 -> bf16 partials
    gemm_bt<<<dim3(12, 32, 2), 256, 0, stream>>>(xn_bf, wqkv_bf, qkv_part,
                                                 4096, 1536, 1024, 512);
    qkv_post_kernel<<<4096, 256, 0, stream>>>(qkv_part, qnw, knw, Qb, Kb, Vb);
    vtrans_kernel<<<256, 256, 0, stream>>>(Vb, Vt);
    flash_kernel<<<dim3(32, 16, 2), 512, 0, stream>>>(Qb, Kb, Vt, att_bf);
    // out-proj, split-K=2 -> bf16 partials
    gemm_bt<<<dim3(8, 32, 2), 256, 0, stream>>>(att_bf, wo_bf, wo_part,
                                                4096, 1024, 1024, 512);
    fuse_attn_kernel<<<4096, 256, 0, stream>>>(x, wo_part, ascale, fnw, h_f, xn8);
    // w1|w3 fp8-MX GEMM with fused SwiGLU -> gsw8 (256x256 tiles, 512 blocks = 2 full CU rounds)
    gemm_fp8<1><<<dim3(32, 16, 1), 512, 0, stream>>>(xn8, w13_8, nullptr, gsw8,
                                                     4096, 8192, 1024, 1024);
    // w2 fp8-MX GEMM, split-K=4 -> bf16 partials (256 blocks = exactly 1 CU round)
    gemm_fp8<0><<<dim3(4, 16, 4), 512, 0, stream>>>(gsw8, w2_8, w2_part, nullptr,
                                                    4096, 1024, 4096, 1024);
    fuse_ffn_kernel<<<4096, 256, 0, stream>>>(h_f, w2_part, fscale, out);
}